// Round 2
// baseline (739.278 us; speedup 1.0000x reference)
//
#include <hip/hip_runtime.h>
#include <hip/hip_cooperative_groups.h>

namespace cg = cooperative_groups;

#define N_NODES 50000
#define N_EDGES 800000
#define D 128
#define ROWS 32
#define PMASK 0xFFFFF  // low 20 bits of packed offs = position; high 12 = degree
#define NCHUNKS 196    // 196*256 = 50176 >= 50000
#define PRE_BLOCKS 1024

typedef int   v4i __attribute__((ext_vector_type(4)));
typedef float v4f __attribute__((ext_vector_type(4)));

// Buffer reuse map:
//  d_ws  [0, 200000)      : offs (int[50000])                    (known-safe size)
//  d_out [0, 3.2M)        : dcopy (int[800000], dst copy)        dead before fused writes
//  d_out [3.4M, +784)     : bsums (int[196])                     dead before fused writes
//  dstbuf[0, 1.6M)        : col (ushort[800000])  — dst input is dead after phase 1 copy
//  dstbuf[1.6M, 1.8M)     : normArr (float[50000])
//  dstbuf[1.8M, +128K)    : whi1/wlo1/whi2/wlo2 (bf16 hi/lo split weights, 32KB each)

// ---- round-to-nearest-even f32 -> bf16 helpers ------------------------------
__device__ __forceinline__ unsigned short bf_rne(float v) {
    unsigned u = __float_as_uint(v);
    u += 0x7FFFu + ((u >> 16) & 1u);
    return (unsigned short)(u >> 16);
}
__device__ __forceinline__ float bf_up(unsigned short h) {
    return __uint_as_float((unsigned)h << 16);
}
__device__ __forceinline__ void split_pack(float a, float b, unsigned& hw, unsigned& lw) {
    unsigned short ha = bf_rne(a);
    unsigned short hb = bf_rne(b);
    unsigned short la = bf_rne(a - bf_up(ha));
    unsigned short lb = bf_rne(b - bf_up(hb));
    hw = (unsigned)ha | ((unsigned)hb << 16);
    lw = (unsigned)la | ((unsigned)lb << 16);
}

// ------------- ONE cooperative kernel: zero+hist+scan+sort+prep --------------
__global__ __launch_bounds__(256) void preprocess(
    const int4* __restrict__ src4, const int4* __restrict__ dst4,
    int* __restrict__ offs, int4* __restrict__ dcopy,
    unsigned short* __restrict__ col, float* __restrict__ normArr,
    const float* __restrict__ w1, const float* __restrict__ w2,
    unsigned short* __restrict__ whi1, unsigned short* __restrict__ wlo1,
    unsigned short* __restrict__ whi2, unsigned short* __restrict__ wlo2,
    int* __restrict__ bsums) {
    cg::grid_group grid = cg::this_grid();
    __shared__ int s[256];
    const int t = threadIdx.x, b = blockIdx.x;
    const int gid = b * 256 + t;
    const int gs = PRE_BLOCKS * 256;

    // phase 0: zero offs (replaces hipMemsetAsync)
    for (int i = gid; i < N_NODES; i += gs) offs[i] = 0;
    grid.sync();

    // phase 1: histogram of dst + copy dst -> d_out scratch (read once, use twice)
    for (int e = gid; e < N_EDGES / 4; e += gs) {
        int4 d = dst4[e];
        dcopy[e] = d;
        atomicAdd(&offs[d.x], 1);
        atomicAdd(&offs[d.y], 1);
        atomicAdd(&offs[d.z], 1);
        atomicAdd(&offs[d.w], 1);
    }
    grid.sync();

    // phase 2: per-256-chunk sums
    if (b < NCHUNKS) {
        int i = b * 256 + t;
        int v = (i < N_NODES) ? offs[i] : 0;
        s[t] = v;
        __syncthreads();
        for (int o = 128; o > 0; o >>= 1) {
            if (t < o) s[t] += s[t + o];
            __syncthreads();
        }
        if (t == 0) bsums[b] = s[0];
    }
    grid.sync();

    // phase 3: parallel cross-chunk base + in-chunk scan + deg packing
    // result: offs[i] = (deg_i << 20) | exclusive_start_i
    if (b < NCHUNKS) {
        int i = b * 256 + t;
        int v = (i < N_NODES) ? offs[i] : 0;
        int part = (t < b) ? bsums[t] : 0;  // b <= 195 < 256
        s[t] = part;
        __syncthreads();
        for (int o = 128; o > 0; o >>= 1) {
            if (t < o) s[t] += s[t + o];
            __syncthreads();
        }
        int base = s[0];
        __syncthreads();
        s[t] = v;
        __syncthreads();
        for (int o = 1; o < 256; o <<= 1) {
            int u = (t >= o) ? s[t - o] : 0;
            __syncthreads();
            s[t] += u;
            __syncthreads();
        }
        int excl = s[t] - v;
        if (i < N_NODES) offs[i] = (v << 20) | (base + excl);
    }
    grid.sync();

    // phase 4: counting sort — col[p] = src sorted by dst, written DIRECTLY
    // into the (now dead) dst input buffer. atomicAdd bumps low 20 bits only
    // (end <= 800000 < 2^20, never carries into deg field).
    for (int e = gid; e < N_EDGES / 4; e += gs) {
        int4 sv = src4[e];
        int4 d = dcopy[e];
        int p;
        p = atomicAdd(&offs[d.x], 1); col[p & PMASK] = (unsigned short)sv.x;
        p = atomicAdd(&offs[d.y], 1); col[p & PMASK] = (unsigned short)sv.y;
        p = atomicAdd(&offs[d.z], 1); col[p & PMASK] = (unsigned short)sv.z;
        p = atomicAdd(&offs[d.w], 1); col[p & PMASK] = (unsigned short)sv.w;
    }
    grid.sync();

    // phase 5: normArr + bf16 hi/lo split of both weight matrices
    for (int n = gid; n < N_NODES; n += gs)
        normArr[n] = rsqrtf(fmaxf((float)(offs[n] >> 20), 1.0f));
    for (int m = gid; m < 2 * D * D; m += gs) {
        int sel = m >> 14;  // 0: w1, 1: w2 (16384 elements each)
        int j = m & 16383;
        float v = sel ? w2[j] : w1[j];
        unsigned short h = bf_rne(v);
        unsigned short lo = bf_rne(v - bf_up(h));
        if (sel) { whi2[j] = h; wlo2[j] = lo; }
        else     { whi1[j] = h; wlo1[j] = lo; }
    }
}

// -------- fused CSR gather (8-wide chains) + bf16x3 MFMA MLP, 512 thr --------
// LDS A tiles XOR-swizzled: phys_byte(row, logical_byte) = logical_byte ^ ((row&15)<<4)
// so MFMA frag reads (16 lanes x same 16B column, 256B row stride) are conflict-free.
__global__ __launch_bounds__(512) void fused_gather_mlp(
    const float* __restrict__ x, const unsigned short* __restrict__ col,
    const float* __restrict__ normArr, const int* __restrict__ offs,
    float* __restrict__ io,
    const unsigned short* __restrict__ whi1, const unsigned short* __restrict__ wlo1,
    const float* __restrict__ b1,
    const unsigned short* __restrict__ whi2, const unsigned short* __restrict__ wlo2,
    const float* __restrict__ b2) {
    __shared__ __align__(16) unsigned short Ahi[ROWS][D];  // 8 KB
    __shared__ __align__(16) unsigned short Alo[ROWS][D];  // 8 KB
    int row_base = blockIdx.x * ROWS;
    int t = threadIdx.x;
    int tx = t & 31;   // feature quad 4*tx..4*tx+3
    int g = t >> 5;    // row group 0..15

    // ---------------- gather phase: 16 groups x 2 rows each ------------------
    for (int rr = g; rr < ROWS; rr += 16) {
        int row = row_base + rr;
        float4 acc = make_float4(0.f, 0.f, 0.f, 0.f);
        if (row < N_NODES) {
            int start = row ? (offs[row - 1] & PMASK) : 0;
            int end = offs[row] & PMASK;
            float nr = normArr[row];
            int l = end - 1;
            for (int j = start; j < end; j += 8) {
                int i1 = min(j + 1, l), i2 = min(j + 2, l), i3 = min(j + 3, l);
                int i4 = min(j + 4, l), i5 = min(j + 5, l), i6 = min(j + 6, l);
                int i7 = min(j + 7, l);
                int s0 = col[j],  s1 = col[i1], s2 = col[i2], s3 = col[i3];
                int s4 = col[i4], s5 = col[i5], s6 = col[i6], s7 = col[i7];
                float n0 = normArr[s0];
                float n1 = (j + 1 < end) ? normArr[s1] : 0.f;
                float n2 = (j + 2 < end) ? normArr[s2] : 0.f;
                float n3 = (j + 3 < end) ? normArr[s3] : 0.f;
                float n4 = (j + 4 < end) ? normArr[s4] : 0.f;
                float n5 = (j + 5 < end) ? normArr[s5] : 0.f;
                float n6 = (j + 6 < end) ? normArr[s6] : 0.f;
                float n7 = (j + 7 < end) ? normArr[s7] : 0.f;
                float4 x0 = *(const float4*)(x + (size_t)s0 * D + 4 * tx);
                float4 x1 = *(const float4*)(x + (size_t)s1 * D + 4 * tx);
                float4 x2 = *(const float4*)(x + (size_t)s2 * D + 4 * tx);
                float4 x3 = *(const float4*)(x + (size_t)s3 * D + 4 * tx);
                float4 x4 = *(const float4*)(x + (size_t)s4 * D + 4 * tx);
                float4 x5 = *(const float4*)(x + (size_t)s5 * D + 4 * tx);
                float4 x6 = *(const float4*)(x + (size_t)s6 * D + 4 * tx);
                float4 x7 = *(const float4*)(x + (size_t)s7 * D + 4 * tx);
                acc.x += x0.x * n0 + x1.x * n1 + x2.x * n2 + x3.x * n3
                       + x4.x * n4 + x5.x * n5 + x6.x * n6 + x7.x * n7;
                acc.y += x0.y * n0 + x1.y * n1 + x2.y * n2 + x3.y * n3
                       + x4.y * n4 + x5.y * n5 + x6.y * n6 + x7.y * n7;
                acc.z += x0.z * n0 + x1.z * n1 + x2.z * n2 + x3.z * n3
                       + x4.z * n4 + x5.z * n5 + x6.z * n6 + x7.z * n7;
                acc.w += x0.w * n0 + x1.w * n1 + x2.w * n2 + x3.w * n3
                       + x4.w * n4 + x5.w * n5 + x6.w * n6 + x7.w * n7;
            }
            acc.x *= nr; acc.y *= nr; acc.z *= nr; acc.w *= nr;
        }
        unsigned hw0, lw0, hw1, lw1;
        split_pack(acc.x, acc.y, hw0, lw0);
        split_pack(acc.z, acc.w, hw1, lw1);
        int byte = (8 * tx) ^ ((rr & 15) << 4);
        *(uint2*)((char*)&Ahi[rr][0] + byte) = make_uint2(hw0, hw1);
        *(uint2*)((char*)&Alo[rr][0] + byte) = make_uint2(lw0, lw1);
    }
    __syncthreads();

    // ---------------- MFMA MLP phase: 8 waves ---------------------------------
    // wave wv -> row tile rt=(wv&1)*16, col 32-block cb=(wv>>1)*32.
    // mfma_f32_16x16x32_bf16: A row = lane&15, k = (lane>>4)*8 + i (8 consecutive);
    // B col = lane&15, same k;  D col = lane&15, row = (lane>>4)*4 + reg.
    int l = t & 63;
    int wv = t >> 6;
    int rt = (wv & 1) << 4;
    int cb = (wv >> 1) << 5;
    int l15 = l & 15;
    int kq = l >> 4;  // 0..3
    const char* phiA = (const char*)&Ahi[rt + l15][0];
    const char* ploA = (const char*)&Alo[rt + l15][0];

    v4i ahi[4], alo[4];
#pragma unroll
    for (int kt = 0; kt < 4; ++kt) {
        int off = ((((kt << 2) | kq) ^ l15) << 4);
        ahi[kt] = *(const v4i*)(phiA + off);
        alo[kt] = *(const v4i*)(ploA + off);
    }
    __syncthreads();  // all waves captured A; LDS may be overwritten with H

    // ---- layer 1: H = relu(A @ w1^T + b1), hi/lo split back into LDS --------
#pragma unroll
    for (int ct = 0; ct < 2; ++ct) {
        int c = cb + (ct << 4) + l15;
        float bv = b1[c];
        v4f acc = {bv, bv, bv, bv};
        const unsigned short* wh = whi1 + c * D + (kq << 3);
        const unsigned short* wl = wlo1 + c * D + (kq << 3);
#pragma unroll
        for (int kt = 0; kt < 4; ++kt) {
            v4i bh = *(const v4i*)(wh + (kt << 5));
            v4i bl = *(const v4i*)(wl + (kt << 5));
            asm volatile("v_mfma_f32_16x16x32_bf16 %0, %1, %2, %0" : "+v"(acc) : "v"(ahi[kt]), "v"(bh));
            asm volatile("v_mfma_f32_16x16x32_bf16 %0, %1, %2, %0" : "+v"(acc) : "v"(alo[kt]), "v"(bh));
            asm volatile("v_mfma_f32_16x16x32_bf16 %0, %1, %2, %0" : "+v"(acc) : "v"(ahi[kt]), "v"(bl));
        }
        asm volatile("s_nop 7\n\ts_nop 7" : "+v"(acc));  // MFMA->VALU RAW hazard insurance
#pragma unroll
        for (int r = 0; r < 4; ++r) {
            float v = fmaxf(acc[r], 0.0f);
            unsigned short hv = bf_rne(v);
            unsigned short lv = bf_rne(v - bf_up(hv));
            int ro = rt + (kq << 2) + r;
            int byte = (2 * c) ^ ((ro & 15) << 4);
            *(unsigned short*)((char*)&Ahi[ro][0] + byte) = hv;
            *(unsigned short*)((char*)&Alo[ro][0] + byte) = lv;
        }
    }
    __syncthreads();  // H visible to all waves

#pragma unroll
    for (int kt = 0; kt < 4; ++kt) {
        int off = ((((kt << 2) | kq) ^ l15) << 4);
        ahi[kt] = *(const v4i*)(phiA + off);
        alo[kt] = *(const v4i*)(ploA + off);
    }

    // ---- layer 2: out = relu(H @ w2^T + b2) ---------------------------------
#pragma unroll
    for (int ct = 0; ct < 2; ++ct) {
        int c = cb + (ct << 4) + l15;
        float bv = b2[c];
        v4f acc = {bv, bv, bv, bv};
        const unsigned short* wh = whi2 + c * D + (kq << 3);
        const unsigned short* wl = wlo2 + c * D + (kq << 3);
#pragma unroll
        for (int kt = 0; kt < 4; ++kt) {
            v4i bh = *(const v4i*)(wh + (kt << 5));
            v4i bl = *(const v4i*)(wl + (kt << 5));
            asm volatile("v_mfma_f32_16x16x32_bf16 %0, %1, %2, %0" : "+v"(acc) : "v"(ahi[kt]), "v"(bh));
            asm volatile("v_mfma_f32_16x16x32_bf16 %0, %1, %2, %0" : "+v"(acc) : "v"(alo[kt]), "v"(bh));
            asm volatile("v_mfma_f32_16x16x32_bf16 %0, %1, %2, %0" : "+v"(acc) : "v"(ahi[kt]), "v"(bl));
        }
        asm volatile("s_nop 7\n\ts_nop 7" : "+v"(acc));
#pragma unroll
        for (int r = 0; r < 4; ++r) {
            int ro = row_base + rt + (kq << 2) + r;
            if (ro < N_NODES)
                io[(size_t)ro * D + c] = fmaxf(acc[r], 0.0f);
        }
    }
}

extern "C" void kernel_launch(void* const* d_in, const int* in_sizes, int n_in,
                              void* d_out, int out_size, void* d_ws, size_t ws_size,
                              hipStream_t stream) {
    const float* x      = (const float*)d_in[0];
    const int*   src    = (const int*)d_in[1];
    int*         dstbuf = (int*)d_in[2];   // reused as scratch after phase 1
    const float* w_conv = (const float*)d_in[3];
    const float* b_conv = (const float*)d_in[4];
    const float* w_lin  = (const float*)d_in[5];
    const float* b_lin  = (const float*)d_in[6];
    float* out = (float*)d_out;

    int* offs = (int*)d_ws;  // 50000 ints = 200,000 B (known-safe size)
    const int4* src4 = (const int4*)src;
    const int4* dst4 = (const int4*)dstbuf;
    int4* dcopy = (int4*)d_out;                          // 3.2 MB scratch
    int* bsums = (int*)((char*)d_out + 3400000);         // 196 ints scratch
    unsigned short* col = (unsigned short*)dstbuf;
    float* normArr = (float*)((char*)dstbuf + 1600000);
    unsigned short* whi1 = (unsigned short*)((char*)dstbuf + 1800000);
    unsigned short* wlo1 = (unsigned short*)((char*)dstbuf + 1832768);
    unsigned short* whi2 = (unsigned short*)((char*)dstbuf + 1865536);
    unsigned short* wlo2 = (unsigned short*)((char*)dstbuf + 1898304);

    void* args[] = {
        (void*)&src4, (void*)&dst4, (void*)&offs, (void*)&dcopy,
        (void*)&col, (void*)&normArr, (void*)&w_conv, (void*)&w_lin,
        (void*)&whi1, (void*)&wlo1, (void*)&whi2, (void*)&wlo2, (void*)&bsums};
    hipLaunchCooperativeKernel((void*)preprocess, dim3(PRE_BLOCKS), dim3(256),
                               args, 0, stream);

    fused_gather_mlp<<<(N_NODES + ROWS - 1) / ROWS, 512, 0, stream>>>(
        x, col, normArr, offs, out, whi1, wlo1, b_conv, whi2, wlo2, b_lin);
}

// Round 3
// 268.933 us; speedup vs baseline: 2.7489x; 2.7489x over previous
//
#include <hip/hip_runtime.h>

#define N_NODES 50000
#define N_EDGES 800000
#define D 128
#define ROWS 32
#define PMASK 0xFFFFF   // low 20 bits of packed offs = position; high 12 = degree
#define SCAN_BLOCKS 49  // 49*1024 = 50176 >= 50000
#define EDGE_BLOCKS 782 // ceil(200000/256) quads
#define WSPLIT_BLOCKS 128 // 128*256 = 32768 = 2*D*D

typedef int   v4i __attribute__((ext_vector_type(4)));
typedef float v4f __attribute__((ext_vector_type(4)));

// Buffer reuse map:
//  d_ws  [0, 200000)      : offs (int[50000])                  (known-safe size)
//  d_out [0, 3.2M)        : dcopy (int[800000], dst copy)      dead before fused writes
//  d_out [3.4M, +196)     : bsums (int[49])                    dead before fused writes
//  dstbuf[0, 1.6M)        : col (ushort[800000]) — dst input dead after hist's dcopy
//  dstbuf[1.6M, 1.8M)     : normArr (float[50000])
//  dstbuf[1.8M, +128K)    : whi1/wlo1/whi2/wlo2 (bf16 hi/lo split weights, 32KB each)

// ---- round-to-nearest-even f32 -> bf16 helpers ------------------------------
__device__ __forceinline__ unsigned short bf_rne(float v) {
    unsigned u = __float_as_uint(v);
    u += 0x7FFFu + ((u >> 16) & 1u);
    return (unsigned short)(u >> 16);
}
__device__ __forceinline__ float bf_up(unsigned short h) {
    return __uint_as_float((unsigned)h << 16);
}
__device__ __forceinline__ void split_pack(float a, float b, unsigned& hw, unsigned& lw) {
    unsigned short ha = bf_rne(a);
    unsigned short hb = bf_rne(b);
    unsigned short la = bf_rne(a - bf_up(ha));
    unsigned short lb = bf_rne(b - bf_up(hb));
    hw = (unsigned)ha | ((unsigned)hb << 16);
    lw = (unsigned)la | ((unsigned)lb << 16);
}

// ---- hist of dst (int4) + dcopy to d_out + bf16 weight split in spare blocks
__global__ void hist_kernel(const int4* __restrict__ dst4, int* __restrict__ offs,
                            int4* __restrict__ dcopy,
                            const float* __restrict__ w1, const float* __restrict__ w2,
                            unsigned short* __restrict__ whi1, unsigned short* __restrict__ wlo1,
                            unsigned short* __restrict__ whi2, unsigned short* __restrict__ wlo2) {
    int b = blockIdx.x, t = threadIdx.x;
    if (b < EDGE_BLOCKS) {
        int e = b * 256 + t;
        if (e < N_EDGES / 4) {
            int4 d = dst4[e];
            dcopy[e] = d;  // dst input becomes dead scratch after this kernel
            atomicAdd(&offs[d.x], 1);
            atomicAdd(&offs[d.y], 1);
            atomicAdd(&offs[d.z], 1);
            atomicAdd(&offs[d.w], 1);
        }
    } else {
        // weight split depends only on inputs — do it here, off the critical path
        int m = (b - EDGE_BLOCKS) * 256 + t;  // 0 .. 32767
        int sel = m >> 14;  // 0: w1, 1: w2 (16384 elements each)
        int j = m & 16383;
        float v = sel ? w2[j] : w1[j];
        unsigned short h = bf_rne(v);
        unsigned short lo = bf_rne(v - bf_up(h));
        if (sel) { whi2[j] = h; wlo2[j] = lo; }
        else     { whi1[j] = h; wlo1[j] = lo; }
    }
}

// ---------------- scan stage 1: per-1024-chunk sums --------------------------
__global__ __launch_bounds__(1024) void scan_reduce(const int* __restrict__ a,
                                                    int* __restrict__ bsums) {
    __shared__ int red[1024];
    int t = threadIdx.x;
    int i = blockIdx.x * 1024 + t;
    red[t] = (i < N_NODES) ? a[i] : 0;
    __syncthreads();
    for (int off = 512; off > 0; off >>= 1) {
        if (t < off) red[t] += red[t + off];
        __syncthreads();
    }
    if (t == 0) bsums[blockIdx.x] = red[0];
}

// -------- scan stage 2: in-block scan + cross-chunk base + deg packing -------
// result: a[i] = (deg_i << 20) | exclusive_start_i ; also writes normArr
__global__ __launch_bounds__(1024) void scan_apply(int* __restrict__ a,
                                                   const int* __restrict__ bsums,
                                                   float* __restrict__ normArr) {
    __shared__ int s[1024];
    int t = threadIdx.x, bid = blockIdx.x;
    int i = bid * 1024 + t;
    int v = (i < N_NODES) ? a[i] : 0;
    s[t] = v;
    __syncthreads();
    for (int off = 1; off < 1024; off <<= 1) {
        int u = (t >= off) ? s[t - off] : 0;
        __syncthreads();
        s[t] += u;
        __syncthreads();
    }
    int excl = s[t] - v;
    int base = 0;  // wave-uniform loop -> scalar loads
    for (int b = 0; b < bid; ++b) base += bsums[b];
    if (i < N_NODES) {
        normArr[i] = rsqrtf(fmaxf((float)v, 1.0f));  // deg in hand here
        a[i] = (v << 20) | (base + excl);
    }
}

// ---- counting sort: col[p] = src sorted by dst, written DIRECTLY to dstbuf --
// (dst values come from dcopy in d_out, so no read/write race with col)
__global__ void sort_kernel(const int4* __restrict__ src4, const int4* __restrict__ dcopy,
                            int* __restrict__ offs, unsigned short* __restrict__ col) {
    int e = blockIdx.x * blockDim.x + threadIdx.x;
    if (e < N_EDGES / 4) {
        int4 s = src4[e];
        int4 d = dcopy[e];
        int p;
        p = atomicAdd(&offs[d.x], 1); col[p & PMASK] = (unsigned short)s.x;
        p = atomicAdd(&offs[d.y], 1); col[p & PMASK] = (unsigned short)s.y;
        p = atomicAdd(&offs[d.z], 1); col[p & PMASK] = (unsigned short)s.z;
        p = atomicAdd(&offs[d.w], 1); col[p & PMASK] = (unsigned short)s.w;
    }
}

// -------- fused CSR gather (8-wide chains) + bf16x3 MFMA MLP, 512 thr --------
// LDS A tiles XOR-swizzled: phys_byte(row, logical_byte) = logical_byte ^ ((row&15)<<4)
// so MFMA frag reads (16 lanes x same 16B column, 256B row stride) are conflict-free.
__global__ __launch_bounds__(512) void fused_gather_mlp(
    const float* __restrict__ x, const unsigned short* __restrict__ col,
    const float* __restrict__ normArr, const int* __restrict__ offs,
    float* __restrict__ io,
    const unsigned short* __restrict__ whi1, const unsigned short* __restrict__ wlo1,
    const float* __restrict__ b1,
    const unsigned short* __restrict__ whi2, const unsigned short* __restrict__ wlo2,
    const float* __restrict__ b2) {
    __shared__ __align__(16) unsigned short Ahi[ROWS][D];  // 8 KB
    __shared__ __align__(16) unsigned short Alo[ROWS][D];  // 8 KB
    int row_base = blockIdx.x * ROWS;
    int t = threadIdx.x;
    int tx = t & 31;   // feature quad 4*tx..4*tx+3
    int g = t >> 5;    // row group 0..15

    // ---------------- gather phase: 16 groups x 2 rows each ------------------
    for (int rr = g; rr < ROWS; rr += 16) {
        int row = row_base + rr;
        float4 acc = make_float4(0.f, 0.f, 0.f, 0.f);
        if (row < N_NODES) {
            int start = row ? (offs[row - 1] & PMASK) : 0;
            int end = offs[row] & PMASK;
            float nr = normArr[row];
            int l = end - 1;
            for (int j = start; j < end; j += 8) {
                int i1 = min(j + 1, l), i2 = min(j + 2, l), i3 = min(j + 3, l);
                int i4 = min(j + 4, l), i5 = min(j + 5, l), i6 = min(j + 6, l);
                int i7 = min(j + 7, l);
                int s0 = col[j],  s1 = col[i1], s2 = col[i2], s3 = col[i3];
                int s4 = col[i4], s5 = col[i5], s6 = col[i6], s7 = col[i7];
                float n0 = normArr[s0];
                float n1 = (j + 1 < end) ? normArr[s1] : 0.f;
                float n2 = (j + 2 < end) ? normArr[s2] : 0.f;
                float n3 = (j + 3 < end) ? normArr[s3] : 0.f;
                float n4 = (j + 4 < end) ? normArr[s4] : 0.f;
                float n5 = (j + 5 < end) ? normArr[s5] : 0.f;
                float n6 = (j + 6 < end) ? normArr[s6] : 0.f;
                float n7 = (j + 7 < end) ? normArr[s7] : 0.f;
                float4 x0 = *(const float4*)(x + (size_t)s0 * D + 4 * tx);
                float4 x1 = *(const float4*)(x + (size_t)s1 * D + 4 * tx);
                float4 x2 = *(const float4*)(x + (size_t)s2 * D + 4 * tx);
                float4 x3 = *(const float4*)(x + (size_t)s3 * D + 4 * tx);
                float4 x4 = *(const float4*)(x + (size_t)s4 * D + 4 * tx);
                float4 x5 = *(const float4*)(x + (size_t)s5 * D + 4 * tx);
                float4 x6 = *(const float4*)(x + (size_t)s6 * D + 4 * tx);
                float4 x7 = *(const float4*)(x + (size_t)s7 * D + 4 * tx);
                acc.x += x0.x * n0 + x1.x * n1 + x2.x * n2 + x3.x * n3
                       + x4.x * n4 + x5.x * n5 + x6.x * n6 + x7.x * n7;
                acc.y += x0.y * n0 + x1.y * n1 + x2.y * n2 + x3.y * n3
                       + x4.y * n4 + x5.y * n5 + x6.y * n6 + x7.y * n7;
                acc.z += x0.z * n0 + x1.z * n1 + x2.z * n2 + x3.z * n3
                       + x4.z * n4 + x5.z * n5 + x6.z * n6 + x7.z * n7;
                acc.w += x0.w * n0 + x1.w * n1 + x2.w * n2 + x3.w * n3
                       + x4.w * n4 + x5.w * n5 + x6.w * n6 + x7.w * n7;
            }
            acc.x *= nr; acc.y *= nr; acc.z *= nr; acc.w *= nr;
        }
        unsigned hw0, lw0, hw1, lw1;
        split_pack(acc.x, acc.y, hw0, lw0);
        split_pack(acc.z, acc.w, hw1, lw1);
        int byte = (8 * tx) ^ ((rr & 15) << 4);
        *(uint2*)((char*)&Ahi[rr][0] + byte) = make_uint2(hw0, hw1);
        *(uint2*)((char*)&Alo[rr][0] + byte) = make_uint2(lw0, lw1);
    }
    __syncthreads();

    // ---------------- MFMA MLP phase: 8 waves ---------------------------------
    // wave wv -> row tile rt=(wv&1)*16, col 32-block cb=(wv>>1)*32.
    // mfma_f32_16x16x32_bf16: A row = lane&15, k = (lane>>4)*8 + i (8 consecutive);
    // B col = lane&15, same k;  D col = lane&15, row = (lane>>4)*4 + reg.
    int l = t & 63;
    int wv = t >> 6;
    int rt = (wv & 1) << 4;
    int cb = (wv >> 1) << 5;
    int l15 = l & 15;
    int kq = l >> 4;  // 0..3
    const char* phiA = (const char*)&Ahi[rt + l15][0];
    const char* ploA = (const char*)&Alo[rt + l15][0];

    v4i ahi[4], alo[4];
#pragma unroll
    for (int kt = 0; kt < 4; ++kt) {
        int off = ((((kt << 2) | kq) ^ l15) << 4);
        ahi[kt] = *(const v4i*)(phiA + off);
        alo[kt] = *(const v4i*)(ploA + off);
    }
    __syncthreads();  // all waves captured A; LDS may be overwritten with H

    // ---- layer 1: H = relu(A @ w1^T + b1), hi/lo split back into LDS --------
#pragma unroll
    for (int ct = 0; ct < 2; ++ct) {
        int c = cb + (ct << 4) + l15;
        float bv = b1[c];
        v4f acc = {bv, bv, bv, bv};
        const unsigned short* wh = whi1 + c * D + (kq << 3);
        const unsigned short* wl = wlo1 + c * D + (kq << 3);
#pragma unroll
        for (int kt = 0; kt < 4; ++kt) {
            v4i bh = *(const v4i*)(wh + (kt << 5));
            v4i bl = *(const v4i*)(wl + (kt << 5));
            asm volatile("v_mfma_f32_16x16x32_bf16 %0, %1, %2, %0" : "+v"(acc) : "v"(ahi[kt]), "v"(bh));
            asm volatile("v_mfma_f32_16x16x32_bf16 %0, %1, %2, %0" : "+v"(acc) : "v"(alo[kt]), "v"(bh));
            asm volatile("v_mfma_f32_16x16x32_bf16 %0, %1, %2, %0" : "+v"(acc) : "v"(ahi[kt]), "v"(bl));
        }
        asm volatile("s_nop 7\n\ts_nop 7" : "+v"(acc));  // MFMA->VALU RAW hazard insurance
#pragma unroll
        for (int r = 0; r < 4; ++r) {
            float v = fmaxf(acc[r], 0.0f);
            unsigned short hv = bf_rne(v);
            unsigned short lv = bf_rne(v - bf_up(hv));
            int ro = rt + (kq << 2) + r;
            int byte = (2 * c) ^ ((ro & 15) << 4);
            *(unsigned short*)((char*)&Ahi[ro][0] + byte) = hv;
            *(unsigned short*)((char*)&Alo[ro][0] + byte) = lv;
        }
    }
    __syncthreads();  // H visible to all waves

#pragma unroll
    for (int kt = 0; kt < 4; ++kt) {
        int off = ((((kt << 2) | kq) ^ l15) << 4);
        ahi[kt] = *(const v4i*)(phiA + off);
        alo[kt] = *(const v4i*)(ploA + off);
    }

    // ---- layer 2: out = relu(H @ w2^T + b2) ---------------------------------
#pragma unroll
    for (int ct = 0; ct < 2; ++ct) {
        int c = cb + (ct << 4) + l15;
        float bv = b2[c];
        v4f acc = {bv, bv, bv, bv};
        const unsigned short* wh = whi2 + c * D + (kq << 3);
        const unsigned short* wl = wlo2 + c * D + (kq << 3);
#pragma unroll
        for (int kt = 0; kt < 4; ++kt) {
            v4i bh = *(const v4i*)(wh + (kt << 5));
            v4i bl = *(const v4i*)(wl + (kt << 5));
            asm volatile("v_mfma_f32_16x16x32_bf16 %0, %1, %2, %0" : "+v"(acc) : "v"(ahi[kt]), "v"(bh));
            asm volatile("v_mfma_f32_16x16x32_bf16 %0, %1, %2, %0" : "+v"(acc) : "v"(alo[kt]), "v"(bh));
            asm volatile("v_mfma_f32_16x16x32_bf16 %0, %1, %2, %0" : "+v"(acc) : "v"(ahi[kt]), "v"(bl));
        }
        asm volatile("s_nop 7\n\ts_nop 7" : "+v"(acc));
#pragma unroll
        for (int r = 0; r < 4; ++r) {
            int ro = row_base + rt + (kq << 2) + r;
            if (ro < N_NODES)
                io[(size_t)ro * D + c] = fmaxf(acc[r], 0.0f);
        }
    }
}

extern "C" void kernel_launch(void* const* d_in, const int* in_sizes, int n_in,
                              void* d_out, int out_size, void* d_ws, size_t ws_size,
                              hipStream_t stream) {
    const float* x      = (const float*)d_in[0];
    const int*   src    = (const int*)d_in[1];
    int*         dstbuf = (int*)d_in[2];   // reused as scratch after hist's dcopy
    const float* w_conv = (const float*)d_in[3];
    const float* b_conv = (const float*)d_in[4];
    const float* w_lin  = (const float*)d_in[5];
    const float* b_lin  = (const float*)d_in[6];
    float* out = (float*)d_out;

    int* offs = (int*)d_ws;  // 50000 ints = 200,000 B (known-safe size)
    const int4* src4 = (const int4*)src;
    const int4* dst4 = (const int4*)dstbuf;
    int4* dcopy = (int4*)d_out;                          // 3.2 MB scratch, dead before fused
    int* bsums = (int*)((char*)d_out + 3400000);         // 49 ints scratch
    unsigned short* col = (unsigned short*)dstbuf;
    float* normArr = (float*)((char*)dstbuf + 1600000);
    unsigned short* whi1 = (unsigned short*)((char*)dstbuf + 1800000);
    unsigned short* wlo1 = (unsigned short*)((char*)dstbuf + 1832768);
    unsigned short* whi2 = (unsigned short*)((char*)dstbuf + 1865536);
    unsigned short* wlo2 = (unsigned short*)((char*)dstbuf + 1898304);

    hipMemsetAsync(offs, 0, (size_t)N_NODES * sizeof(int), stream);
    hist_kernel<<<EDGE_BLOCKS + WSPLIT_BLOCKS, 256, 0, stream>>>(
        dst4, offs, dcopy, w_conv, w_lin, whi1, wlo1, whi2, wlo2);
    scan_reduce<<<SCAN_BLOCKS, 1024, 0, stream>>>(offs, bsums);
    scan_apply<<<SCAN_BLOCKS, 1024, 0, stream>>>(offs, bsums, normArr);
    sort_kernel<<<(N_EDGES / 4 + 255) / 256, 256, 0, stream>>>(src4, dcopy, offs, col);
    fused_gather_mlp<<<(N_NODES + ROWS - 1) / ROWS, 512, 0, stream>>>(
        x, col, normArr, offs, out, whi1, wlo1, b_conv, whi2, wlo2, b_lin);
}